// Round 22
// baseline (388.113 us; speedup 1.0000x reference)
//
#include <hip/hip_runtime.h>

#define N_NODESC 20000
#define N_EDGESC 320000
#define HC 640
#define NGRAPH 500

typedef unsigned short u16;
typedef unsigned int u32;
typedef __attribute__((ext_vector_type(8))) short bf16x8;
typedef __attribute__((ext_vector_type(4))) float f32x4;

__device__ __forceinline__ float wred_sum(float v){
  #pragma unroll
  for(int o=32;o;o>>=1) v += __shfl_xor(v,o,64);
  return v;
}
__device__ __forceinline__ float lrelu(float x){ return x>0.f? x:0.2f*x; }

__device__ __forceinline__ u16 f2bf(float f){
  u32 u=__float_as_uint(f);
  u32 r=u+0x7FFFu+((u>>16)&1u);
  return (u16)(r>>16);
}
__device__ __forceinline__ float bf2f(u16 s){ return __uint_as_float(((u32)s)<<16); }
__device__ __forceinline__ float bflo(u32 w){ return __uint_as_float(w<<16); }
__device__ __forceinline__ float bfhi(u32 w){ return __uint_as_float(w&0xFFFF0000u); }

__device__ __forceinline__ void gload16(const void* g, void* l){
  __builtin_amdgcn_global_load_lds((const __attribute__((address_space(1))) void*)g,
                                   (__attribute__((address_space(3))) void*)l, 16, 0, 0);
}

// fragment-order offset (u16 units): rows (mult 16), K cols (mult 32).
__device__ __forceinline__ size_t fidx(int r, int k, int KB){
  return ((size_t)(r>>4)*KB + (k>>5))*512 + (((k>>3)&3)*16 + (r&15))*8 + (k&7);
}

// ---------------- graph preprocessing ----------------

__global__ void k_count(const int* __restrict__ dst, int* __restrict__ cnt){
  int i=blockIdx.x*blockDim.x+threadIdx.x;
  if(i>=N_EDGESC) return;
  atomicAdd(&cnt[dst[i]],1);
}

__global__ void k_scan(const int* __restrict__ cnt, int* __restrict__ rptr, int* __restrict__ pos){
  __shared__ int ps[1024];
  int t=threadIdx.x;
  const int CH=20;
  int beg=t*CH, end=min(beg+CH, N_NODESC);
  int s=0;
  for(int i=beg;i<end;i++) s+=cnt[i];
  ps[t]=s; __syncthreads();
  for(int off=1;off<1024;off<<=1){
    int v=(t>=off)? ps[t-off]:0;
    __syncthreads();
    ps[t]+=v;
    __syncthreads();
  }
  int base=ps[t]-s;
  for(int i=beg;i<end;i++){ rptr[i]=base; pos[i]=base; base+=cnt[i]; }
}

// scatter + CSR edge-data resolution in ONE pass
__global__ void k_scatter(const int* __restrict__ dst, const int* __restrict__ src,
                          const float* __restrict__ eattr, int* __restrict__ pos,
                          int* __restrict__ srcE, int* __restrict__ dstC,
                          float* __restrict__ eattrC){
  int i=blockIdx.x*blockDim.x+threadIdx.x;
  if(i>=N_EDGESC) return;
  int d=dst[i];
  int j=atomicAdd(&pos[d],1);
  dstC[j]=d;
  srcE[j]=src[i];
  const float* ep=&eattr[(size_t)i*10];
  float* op=&eattrC[(size_t)j*10];
  #pragma unroll
  for(int k=0;k<10;k++) op[k]=ep[k];
}

__global__ __launch_bounds__(256) void k_loop_attr(const float* __restrict__ eattrC,
    const int* __restrict__ rptr, const int* __restrict__ cnt,
    float* __restrict__ lattr){
  int tid=threadIdx.x, lane=tid&63;
  int n=blockIdx.x*4+(tid>>6);
  if(n>=N_NODESC) return;
  int beg=rptr[n], deg=cnt[n];
  float s[10]={0,0,0,0,0,0,0,0,0,0};
  for(int off=lane; off<deg; off+=64){
    const float* ep=&eattrC[(size_t)(beg+off)*10];
    #pragma unroll
    for(int k=0;k<10;k++) s[k]+=ep[k];
  }
  float inv=1.f/fmaxf((float)deg,1.f);
  #pragma unroll
  for(int k=0;k<10;k++){
    float tot=wred_sum(s[k]);
    if(lane==0) lattr[(size_t)n*10+k]=tot*inv;
  }
}

// ---------------- conversions ----------------

// x [20000][43] -> padded bf16 xb [20000][64]
__global__ void k_padxb(const float* __restrict__ x, u16* __restrict__ xb){
  int idx=blockIdx.x*blockDim.x+threadIdx.x;
  if(idx>=N_NODESC*64) return;
  int n=idx>>6, kk=idx&63;
  float v = kk<43 ? x[n*43+kk] : 0.f;
  xb[idx]=f2bf(v);
}

// all 3 layers' transposed weights, fragment-order within each packed region.
__global__ void k_conv_w3(const float* __restrict__ W0, const float* __restrict__ W1,
                          const float* __restrict__ W2,
                          u16* __restrict__ hi, u16* __restrict__ lo){
  const int R0=HC*64, R1=R0+HC*HC;
  const int TOT=R1+HC*HC;
  int idx=blockIdx.x*blockDim.x+threadIdx.x;
  if(idx>=TOT) return;
  const float* W; int local, KP, KL, base;
  if(idx<R0){ W=W0; local=idx; KP=64; KL=43; base=0; }
  else if(idx<R1){ W=W1; local=idx-R0; KP=HC; KL=HC; base=R0; }
  else { W=W2; local=idx-R1; KP=HC; KL=HC; base=R1; }
  int n=local/KP, kk=local-n*KP;
  float v = kk<KL ? W[(size_t)kk*HC+n] : 0.f;
  u16 h=f2bf(v);
  size_t off=(size_t)base + fidx(n,kk,KP>>5);
  hi[off]=h;
  lo[off]=f2bf(v-bf2f(h));
}

// ---------------- attention-term kernels ----------------

__global__ void k_ve3(const float* __restrict__ We0, const float* __restrict__ ae0,
                      const float* __restrict__ We1, const float* __restrict__ ae1,
                      const float* __restrict__ We2, const float* __restrict__ ae2,
                      float* __restrict__ ve3){
  int t=threadIdx.x;
  if(t>=150) return;
  int L=t/50, r=t-50*L, k=r/5, h=r%5;
  const float* We = (L==0)?We0:(L==1)?We1:We2;
  const float* ae = (L==0)?ae0:(L==1)?ae1:ae2;
  float s=0.f;
  for(int c=0;c<128;c++) s += We[k*HC + h*128 + c]*ae[h*128+c];
  ve3[t]=s;
}

// VS0/VD0 (W0^T a vectors) + cb = dot(bias2,wlin) (wave 5). 384 threads.
__global__ void k_vs0(const float* __restrict__ W0, const float* __restrict__ asrc,
                      const float* __restrict__ adst,
                      const float* __restrict__ bias2, const float* __restrict__ wlin,
                      float* __restrict__ VS, float* __restrict__ VD,
                      float* __restrict__ cb){
  int t=threadIdx.x;
  if(t<320){
    int k=t/5, h=t%5;
    float sv=0.f, dv=0.f;
    if(k<43){
      for(int c=0;c<128;c++){
        float wv=W0[(size_t)k*HC + h*128 + c];
        sv+=wv*asrc[h*128+c];
        dv+=wv*adst[h*128+c];
      }
    }
    VS[t]=sv; VD[t]=dv;
  }else{
    int lane=t-320;
    float s=0.f;
    for(int c=lane;c<HC;c+=64) s+=bias2[c]*wlin[c];
    s=wred_sum(s);
    if(lane==0) cb[0]=s;
  }
}

// V2[k][o] for L2 linear functionals: o=0..4 al(asrc2), 5..9 ar(adst2), 10..14 q(wlin)
__global__ void k_vq2(const float* __restrict__ W2, const float* __restrict__ asrc,
                      const float* __restrict__ adst, const float* __restrict__ wlin,
                      float* __restrict__ V2){
  int t=blockIdx.x*blockDim.x+threadIdx.x;
  if(t>=HC*15) return;
  int k=t/15, o=t-15*k;
  int h=o%5, grp=o/5;
  const float* v = (grp==0)? asrc : (grp==1)? adst : wlin;
  const float* wr=&W2[(size_t)k*HC + h*128];
  const float* vr=&v[h*128];
  float s=0.f;
  for(int c=0;c<128;c++) s+=wr[c]*vr[c];
  V2[t]=s;
}

// al0/ar0 = x @ VS0 / VD0
__global__ __launch_bounds__(256) void k_alar0(const float* __restrict__ x,
    const float* __restrict__ VS, const float* __restrict__ VD,
    float* __restrict__ al, float* __restrict__ ar){
  __shared__ float vs[320], vd[320];
  if(threadIdx.x<320){ vs[threadIdx.x]=VS[threadIdx.x]; vd[threadIdx.x]=VD[threadIdx.x]; }
  __syncthreads();
  int idx=blockIdx.x*blockDim.x+threadIdx.x;
  if(idx>=N_NODESC*5) return;
  int n=idx/5, h=idx-5*n;
  float sa=0.f, sd=0.f;
  const float* xr=&x[(size_t)n*43];
  for(int k=0;k<43;k++){
    float xv=xr[k];
    sa+=xv*vs[k*5+h];
    sd+=xv*vd[k*5+h];
  }
  al[idx]=sa; ar[idx]=sd;
}

// Layers 1/2: aeC; layer 0: wE0 directly (al0/ar0 ready). Also ael3 for all.
__global__ __launch_bounds__(256) void k_edge_terms3(const float* __restrict__ eattrC,
    const float* __restrict__ lattr, const float* __restrict__ ve3,
    const int* __restrict__ srcE, const int* __restrict__ dstC,
    const float* __restrict__ al0, const float* __restrict__ ar0,
    float* __restrict__ aeC3, float* __restrict__ ael3, float* __restrict__ wE0){
  __shared__ float ves[150];
  if(threadIdx.x<150) ves[threadIdx.x]=ve3[threadIdx.x];
  __syncthreads();
  const int NEDGET=N_EDGESC+N_NODESC*5;
  int idx=blockIdx.x*blockDim.x+threadIdx.x;
  if(idx>=3*NEDGET) return;
  int L=idx/NEDGET, r=idx-L*NEDGET;
  const float* vl=&ves[L*50];
  if(r<N_EDGESC){
    float ev[10];
    const float* ep=&eattrC[(size_t)r*10];
    #pragma unroll
    for(int k=0;k<10;k++) ev[k]=ep[k];
    if(L==0){
      int s=srcE[r], d=dstC[r];
      #pragma unroll
      for(int hh=0;hh<5;hh++){
        float sum=0.f;
        #pragma unroll
        for(int k=0;k<10;k++) sum+=ev[k]*vl[k*5+hh];
        wE0[(size_t)r*5+hh]=__expf(lrelu(al0[s*5+hh]+ar0[d*5+hh]+sum));
      }
    }else{
      #pragma unroll
      for(int hh=0;hh<5;hh++){
        float sum=0.f;
        #pragma unroll
        for(int k=0;k<10;k++) sum+=ev[k]*vl[k*5+hh];
        aeC3[(size_t)L*N_EDGESC*5 + (size_t)r*5+hh]=sum;
      }
    }
  }else{
    int t=r-N_EDGESC;
    int n=t/5, h=t-5*n;
    float s=0.f;
    #pragma unroll
    for(int k=0;k<10;k++) s+=lattr[(size_t)n*10+k]*vl[k*5+h];
    ael3[(size_t)L*N_NODESC*5 + t]=s;
  }
}

// per-layer edge softmax weights (edge-parallel) — used for L1 only now
__global__ void k_edgew(const int* __restrict__ srcE, const int* __restrict__ dstC,
                        const float* __restrict__ al, const float* __restrict__ ar,
                        const float* __restrict__ aeC, float* __restrict__ wE){
  int j=blockIdx.x*blockDim.x+threadIdx.x;
  if(j>=N_EDGESC) return;
  int s=srcE[j], d=dstC[j];
  const float* av=&aeC[(size_t)j*5];
  float* wp=&wE[(size_t)j*5];
  #pragma unroll
  for(int h=0;h<5;h++)
    wp[h]=__expf(lrelu(al[s*5+h]+ar[d*5+h]+av[h]));
}

// ---------------- L0: aggregate-then-transform ----------------

__global__ __launch_bounds__(256) void k_aggx(const u16* __restrict__ xb,
    const int* __restrict__ srcE, const int* __restrict__ rptr, const int* __restrict__ cnt,
    const float* __restrict__ al, const float* __restrict__ ar, const float* __restrict__ ael,
    const float* __restrict__ wE,
    u16* __restrict__ aggx, float* __restrict__ den0){
  const size_t HSZ=(size_t)N_NODESC*64;
  int tid=threadIdx.x, lane=tid&63;
  int n=blockIdx.x*4+(tid>>6);
  if(n>=N_NODESC) return;
  float den[5], acc[5];
  #pragma unroll
  for(int h=0;h<5;h++)
    den[h]=__expf(lrelu(al[n*5+h]+ar[n*5+h]+ael[n*5+h]));   // p0
  float xn=bf2f(xb[(size_t)n*64+lane]);
  #pragma unroll
  for(int h=0;h<5;h++) acc[h]=den[h]*xn;
  int beg=rptr[n], end=beg+cnt[n];
  int j=beg;
  for(; j+7<end; j+=8){
    int sj[8]; float xv[8];
    #pragma unroll
    for(int u=0;u<8;u++) sj[u]=srcE[j+u];
    #pragma unroll
    for(int u=0;u<8;u++) xv[u]=bf2f(xb[(size_t)sj[u]*64+lane]);
    #pragma unroll
    for(int u=0;u<8;u++){
      const float* wp=&wE[(size_t)(j+u)*5];
      #pragma unroll
      for(int h=0;h<5;h++){
        float w=wp[h];
        den[h]+=w;
        acc[h]+=w*xv[u];
      }
    }
  }
  for(; j<end; j++){
    int sj=srcE[j];
    float xv=bf2f(xb[(size_t)sj*64+lane]);
    const float* wp=&wE[(size_t)j*5];
    #pragma unroll
    for(int h=0;h<5;h++){
      float w=wp[h];
      den[h]+=w;
      acc[h]+=w*xv;
    }
  }
  size_t fo=fidx(n,lane,2);
  #pragma unroll
  for(int h=0;h<5;h++) aggx[(size_t)h*HSZ+fo]=f2bf(acc[h]);
  if(lane<5) den0[(size_t)n*5+lane]=den[lane];
}

// L0 GEMM on aggregated inputs (per-head), 128x128, 2 K-steps, dbuf.
__global__ __launch_bounds__(256,3) void k_gemm_l0b(
    const u16* __restrict__ AGX,
    const u16* __restrict__ Bhi, const u16* __restrict__ Blo,
    const float* __restrict__ den0, const float* __restrict__ bias,
    u16* __restrict__ A1, int M, int nblk){
  const size_t HSZ=(size_t)N_NODESC*64;
  __shared__ u16 lds[2*3*4096];
  int tid=threadIdx.x;
  int lane=tid&63;
  int w=tid>>6;
  int l15=lane&15, lg=lane>>4;
  int orig=blockIdx.x;
  int q=nblk>>3, r=nblk&7;
  int xcd=orig&7, off=orig>>3;
  int wg=(xcd<r? xcd*(q+1) : r*(q+1)+(xcd-r)*q)+off;
  int by=wg/5, bx=wg-5*by;
  int row0=by*128, col0=bx*128;
  int wr=w>>1, wc=w&1;
  const u16* A=AGX+(size_t)bx*HSZ;

  f32x4 zero = {0.f,0.f,0.f,0.f};
  f32x4 acc[4][4];
  #pragma unroll
  for(int i=0;i<4;i++)
    #pragma unroll
    for(int j=0;j<4;j++) acc[i][j]=zero;

  auto stage=[&](int b, int k0){
    u16* base = lds + b*3*4096;
    int kb=k0>>5;
    #pragma unroll
    for(int c=0;c<2;c++){
      int sb=w+4*c;
      size_t af=((size_t)((row0>>4)+sb)*2 + kb)*512 + lane*8;
      size_t bf=((size_t)((col0>>4)+sb)*2 + kb)*512 + lane*8;
      gload16(A+af, base + sb*512);
      gload16(Bhi+bf, base+4096 + sb*512);
      gload16(Blo+bf, base+8192 + sb*512);
    }
  };

  stage(0,0);
  __syncthreads();
  int cur=0;
  for(int t=0;t<2;t++){
    if(t==0) stage(1,32);
    u16* cb = lds + cur*3*4096;
    bf16x8 ah[4], bh[4], bl[4];
    #pragma unroll
    for(int i=0;i<4;i++){
      ah[i]=*(const bf16x8*)&cb[(wr*4+i)*512 + lane*8];
      bh[i]=*(const bf16x8*)&cb[4096+(wc*4+i)*512 + lane*8];
      bl[i]=*(const bf16x8*)&cb[8192+(wc*4+i)*512 + lane*8];
    }
    #pragma unroll
    for(int i=0;i<4;i++)
      #pragma unroll
      for(int j=0;j<4;j++){
        acc[i][j]=__builtin_amdgcn_mfma_f32_16x16x32_bf16(ah[i],bh[j],acc[i][j],0,0,0);
        acc[i][j]=__builtin_amdgcn_mfma_f32_16x16x32_bf16(ah[i],bl[j],acc[i][j],0,0,0);
      }
    __syncthreads();
    cur^=1;
  }

  #pragma unroll
  for(int i=0;i<4;i++){
    #pragma unroll
    for(int j=0;j<4;j++){
      int col=col0+wc*64+j*16+l15;
      float bv=bias[col];
      #pragma unroll
      for(int rr=0;rr<4;rr++){
        int row=row0+wr*64+i*16+lg*4+rr;
        if(row<M){
          float dv=den0[(size_t)row*5+bx];
          float v=acc[i][j][rr]/(dv+1e-16f)+bv;
          v=fmaxf(v,0.f);
          A1[fidx(row,col,20)]=f2bf(v);
        }
      }
    }
  }
}

// ---------------- L1 GEMM (64x128 tile, fragment-order) ----------------
// Quad-buffered, prefetch distance 2, counted vmcnt, one barrier per K-step.

__global__ __launch_bounds__(256,3) void k_gemm64(
    const u16* __restrict__ A,
    const u16* __restrict__ B,
    const float* __restrict__ asrc, const float* __restrict__ adst,
    u16* __restrict__ hb, float* __restrict__ al, float* __restrict__ ar,
    int M, int KP, int nblk){
  __shared__ u16 lds[4*6144];
  int tid=threadIdx.x;
  int lane=tid&63;
  int w=tid>>6;
  int l15=lane&15, lg=lane>>4;
  int orig=blockIdx.x;
  int q=nblk>>3, r=nblk&7;
  int xcd=orig&7, off=orig>>3;
  int wg=(xcd<r? xcd*(q+1) : r*(q+1)+(xcd-r)*q)+off;
  int by=wg/5, bx=wg-5*by;
  int row0=by*64, col0=bx*128;
  int KB=KP>>5;

  f32x4 zero = {0.f,0.f,0.f,0.f};
  f32x4 acc[4][2];
  #pragma unroll
  for(int i=0;i<4;i++){ acc[i][0]=zero; acc[i][1]=zero; }

  auto stage=[&](int b, int k0){
    u16* base = lds + b*6144;
    int kb=k0>>5;
    size_t af=((size_t)((row0>>4)+w)*KB + kb)*512 + lane*8;
    gload16(A+af, base + w*512);
    #pragma unroll
    for(int c=0;c<2;c++){
      int sb=w+4*c;
      size_t bf=((size_t)((col0>>4)+sb)*KB + kb)*512 + lane*8;
      gload16(B+bf, base+2048 + sb*512);
    }
  };

  int nt=KP/32;
  stage(0,0);
  stage(1,32);
  for(int t=0;t<nt;t++){
    int nb=t+2;
    if(nb<nt) stage(nb&3, nb*32);
    if(nb<nt)      { asm volatile("s_waitcnt vmcnt(6)" ::: "memory"); }
    else if(t+1<nt){ asm volatile("s_waitcnt vmcnt(3)" ::: "memory"); }
    else           { asm volatile("s_waitcnt vmcnt(0)" ::: "memory"); }
    __builtin_amdgcn_sched_barrier(0);
    __builtin_amdgcn_s_barrier();
    u16* cb = lds + (t&3)*6144;
    bf16x8 ah[4], bh[2];
    #pragma unroll
    for(int i=0;i<4;i++) ah[i]=*(const bf16x8*)&cb[i*512 + lane*8];
    #pragma unroll
    for(int j=0;j<2;j++) bh[j]=*(const bf16x8*)&cb[2048+(w*2+j)*512 + lane*8];
    #pragma unroll
    for(int i=0;i<4;i++){
      acc[i][0]=__builtin_amdgcn_mfma_f32_16x16x32_bf16(ah[i],bh[0],acc[i][0],0,0,0);
      acc[i][1]=__builtin_amdgcn_mfma_f32_16x16x32_bf16(ah[i],bh[1],acc[i][1],0,0,0);
    }
  }
  __syncthreads();

  float asv[2], adv[2];
  #pragma unroll
  for(int j=0;j<2;j++){
    int c=col0+w*32+j*16+l15;
    asv[j]=asrc[c]; adv[j]=adst[c];
  }
  #pragma unroll
  for(int i=0;i<4;i++){
    #pragma unroll
    for(int j=0;j<2;j++){
      #pragma unroll
      for(int rr=0;rr<4;rr++){
        int row=row0+i*16+lg*4+rr;
        if(row<M)
          hb[(size_t)row*HC + ((w&1)*32+j*16+l15)*10 + bx*2+(w>>1)]=f2bf(acc[i][j][rr]);
      }
    }
  }
  float* redAl=(float*)lds;
  float* redAr=redAl+256;
  #pragma unroll
  for(int i=0;i<4;i++){
    #pragma unroll
    for(int rr=0;rr<4;rr++){
      float sa=0.f, sd=0.f;
      #pragma unroll
      for(int j=0;j<2;j++){
        sa+=acc[i][j][rr]*asv[j];
        sd+=acc[i][j][rr]*adv[j];
      }
      #pragma unroll
      for(int o=1;o<16;o<<=1){
        sa+=__shfl_xor(sa,o,64); sd+=__shfl_xor(sd,o,64);
      }
      if(l15==0){
        int lr=i*16+lg*4+rr;
        redAl[lr*4+w]=sa; redAr[lr*4+w]=sd;
      }
    }
  }
  __syncthreads();
  if(tid<64){
    int row=row0+tid;
    if(row<M){
      al[(size_t)row*5+bx]=redAl[tid*4]+redAl[tid*4+1]+redAl[tid*4+2]+redAl[tid*4+3];
      ar[(size_t)row*5+bx]=redAr[tid*4]+redAr[tid*4+1]+redAr[tid*4+2]+redAr[tid*4+3];
    }
  }
}

// L1 aggregation FUSED with the L2 linear functionals: one wave per node.
// out1 (after /den+bias+ReLU) is dotted against V2[640][15] in registers ->
// al2/ar2/qn written directly; out1 is never materialized.
__global__ __launch_bounds__(256) void k_agg(const u16* __restrict__ hb, const int* __restrict__ srcE,
    const int* __restrict__ rptr, const int* __restrict__ cnt,
    const float* __restrict__ al, const float* __restrict__ ar, const float* __restrict__ ael,
    const float* __restrict__ wE, const float* __restrict__ bias,
    const float* __restrict__ V2,
    float* __restrict__ al2, float* __restrict__ ar2, float* __restrict__ qn){
  int tid=threadIdx.x, lane=tid&63;
  int n=blockIdx.x*4+(tid>>6);
  if(n>=N_NODESC) return;
  float den[5], acc[10];
  #pragma unroll
  for(int h=0;h<5;h++)
    den[h]=__expf(lrelu(al[n*5+h]+ar[n*5+h]+ael[n*5+h]));
  {
    const u32* sp=(const u32*)(hb+(size_t)n*HC+lane*10);
    #pragma unroll
    for(int j2=0;j2<5;j2++){
      u32 wv=sp[j2];
      acc[2*j2]  =den[j2]*bflo(wv);
      acc[2*j2+1]=den[j2]*bfhi(wv);
    }
  }
  int beg=rptr[n], end=beg+cnt[n];
  int j=beg;
  for(; j+3<end; j+=4){
    int sj[4];
    #pragma unroll
    for(int u=0;u<4;u++) sj[u]=srcE[j+u];
    float w[4][5];
    #pragma unroll
    for(int u=0;u<4;u++){
      const float* wp=&wE[(size_t)(j+u)*5];
      #pragma unroll
      for(int h=0;h<5;h++) w[u][h]=wp[h];
    }
    u32 wv[4][5];
    #pragma unroll
    for(int u=0;u<4;u++){
      const u32* hr=(const u32*)(hb+(size_t)sj[u]*HC+lane*10);
      #pragma unroll
      for(int j2=0;j2<5;j2++) wv[u][j2]=hr[j2];
    }
    #pragma unroll
    for(int u=0;u<4;u++){
      #pragma unroll
      for(int j2=0;j2<5;j2++){
        den[j2]+=w[u][j2];
        acc[2*j2]  +=w[u][j2]*bflo(wv[u][j2]);
        acc[2*j2+1]+=w[u][j2]*bfhi(wv[u][j2]);
      }
    }
  }
  for(; j<end; j++){
    int sj=srcE[j];
    const float* wp=&wE[(size_t)j*5];
    float w[5];
    #pragma unroll
    for(int h=0;h<5;h++){ w[h]=wp[h]; den[h]+=w[h]; }
    const u32* hr=(const u32*)(hb+(size_t)sj*HC+lane*10);
    #pragma unroll
    for(int j2=0;j2<5;j2++){
      u32 wv=hr[j2];
      acc[2*j2]  +=w[j2]*bflo(wv);
      acc[2*j2+1]+=w[j2]*bfhi(wv);
    }
  }
  // epilogue: out1 values -> 15 linear functionals against V2
  float facc[15];
  #pragma unroll
  for(int o=0;o<15;o++) facc[o]=0.f;
  #pragma unroll
  for(int k=0;k<10;k++){
    int ccol=lane+64*k;
    float vv=acc[k]/(den[k>>1]+1e-16f)+bias[ccol];
    vv=fmaxf(vv,0.f);
    const float* vp=&V2[(size_t)ccol*15];
    #pragma unroll
    for(int o=0;o<15;o++) facc[o]+=vv*vp[o];
  }
  #pragma unroll
  for(int o=0;o<15;o++){
    #pragma unroll
    for(int st=1;st<64;st<<=1) facc[o]+=__shfl_xor(facc[o],st,64);
  }
  if(lane==0){
    #pragma unroll
    for(int h=0;h<5;h++){
      al2[(size_t)n*5+h]=facc[h];
      ar2[(size_t)n*5+h]=facc[5+h];
      qn [(size_t)n*5+h]=facc[10+h];
    }
  }
}

// last-layer agg fused with pooling dot (q summary, L2-resident).
__global__ __launch_bounds__(256) void k_agg_last(const float* __restrict__ qn,
    const int* __restrict__ srcE, const int* __restrict__ rptr, const int* __restrict__ cnt,
    const float* __restrict__ al, const float* __restrict__ ar, const float* __restrict__ ael,
    const float* __restrict__ aeC, const float* __restrict__ cb,
    float* __restrict__ pnode){
  int tid=threadIdx.x;
  int sub=tid&15;
  int n=blockIdx.x*16+(tid>>4);
  if(n>=N_NODESC) return;
  float arn[5], den[5], qs[5];
  #pragma unroll
  for(int h=0;h<5;h++) arn[h]=ar[n*5+h];
  #pragma unroll
  for(int h=0;h<5;h++){ den[h]=0.f; qs[h]=0.f; }
  if(sub==0){
    #pragma unroll
    for(int h=0;h<5;h++){
      float pp=__expf(lrelu(al[n*5+h]+arn[h]+ael[n*5+h]));
      den[h]=pp; qs[h]=pp*qn[(size_t)n*5+h];
    }
  }
  int beg=rptr[n], deg=cnt[n];
  for(int off=sub; off<deg; off+=16){
    int j=beg+off;
    int s=srcE[j];
    const float* av=&aeC[(size_t)j*5];
    const float* qv=&qn[(size_t)s*5];
    #pragma unroll
    for(int h=0;h<5;h++){
      float pp=__expf(lrelu(al[s*5+h]+arn[h]+av[h]));
      den[h]+=pp; qs[h]+=pp*qv[h];
    }
  }
  #pragma unroll
  for(int h=0;h<5;h++){
    #pragma unroll
    for(int o=1;o<16;o<<=1){
      den[h]+=__shfl_xor(den[h],o,16);
      qs[h]+=__shfl_xor(qs[h],o,16);
    }
  }
  if(sub==0){
    float s=0.f;
    #pragma unroll
    for(int h=0;h<5;h++) s+=qs[h]/(den[h]+1e-16f);
    pnode[n]=s+cb[0];
  }
}

// per-graph mean over sorted batch segments
__global__ __launch_bounds__(256) void k_graphout(const float* __restrict__ pnode,
    const int* __restrict__ batch, const float* __restrict__ blin,
    float* __restrict__ out){
  int tid=threadIdx.x, lane=tid&63;
  int g=blockIdx.x*4+(tid>>6);
  if(g>=NGRAPH) return;
  auto lb=[&](int val){
    int lo=0, hi=N_NODESC;
    while(lo<hi){ int mid=(lo+hi)>>1; if(batch[mid]<val) lo=mid+1; else hi=mid; }
    return lo;
  };
  int s0=lb(g), s1=lb(g+1);
  float s=0.f;
  for(int i=s0+lane;i<s1;i+=64) s+=pnode[i];
  s=wred_sum(s);
  if(lane==0) out[g]=s/fmaxf((float)(s1-s0),1.f)+blin[0];
}

// ---------------- launch ----------------

extern "C" void kernel_launch(void* const* d_in, const int* in_sizes, int n_in,
                              void* d_out, int out_size, void* d_ws, size_t ws_size,
                              hipStream_t stream){
  const float* x     = (const float*)d_in[0];
  const float* eattr = (const float*)d_in[1];
  const float* W[3]    ={(const float*)d_in[2],(const float*)d_in[8],(const float*)d_in[14]};
  const float* We[3]   ={(const float*)d_in[3],(const float*)d_in[9],(const float*)d_in[15]};
  const float* asrc[3] ={(const float*)d_in[4],(const float*)d_in[10],(const float*)d_in[16]};
  const float* adst[3] ={(const float*)d_in[5],(const float*)d_in[11],(const float*)d_in[17]};
  const float* aedge[3]={(const float*)d_in[6],(const float*)d_in[12],(const float*)d_in[18]};
  const float* bias[3] ={(const float*)d_in[7],(const float*)d_in[13],(const float*)d_in[19]};
  const float* Wlin  = (const float*)d_in[20];
  const float* blin  = (const float*)d_in[21];
  const int* eind    = (const int*)d_in[22];
  const int* srcp    = eind;
  const int* dstp    = eind + N_EDGESC;
  const int* batch   = (const int*)d_in[23];
  float* out = (float*)d_out;

  char* ws=(char*)d_ws;
  size_t o=0;
  auto alloc=[&](size_t bytes)->void*{ void* p=ws+o; o=(o+bytes+255)&~(size_t)255; return p; };
  u16* hb   =(u16*)alloc((size_t)N_NODESC*HC*2);           // h1 node-major (L1 gather)
  u16* Ahi =(u16*)alloc((size_t)N_NODESC*HC*2);            // A1 (fragment-order)
  u16* xb  =(u16*)alloc((size_t)N_NODESC*64*2);            // padded bf16 x
  u16* aggx=(u16*)alloc((size_t)5*N_NODESC*64*2);          // L0 aggregated per-head
  const int WB0=0, WB1=HC*64, WB2=WB1+HC*HC;
  u16* Bthi3=(u16*)alloc((size_t)(WB2+HC*HC)*2);
  u16* Btlo3=(u16*)alloc((size_t)(WB2+HC*HC)*2);
  float* al   =(float*)alloc((size_t)N_NODESC*5*4);
  float* ar   =(float*)alloc((size_t)N_NODESC*5*4);
  float* al2  =(float*)alloc((size_t)N_NODESC*5*4);
  float* ar2  =(float*)alloc((size_t)N_NODESC*5*4);
  float* qn   =(float*)alloc((size_t)N_NODESC*5*4);
  float* den0 =(float*)alloc((size_t)N_NODESC*5*4);
  float* ael3 =(float*)alloc((size_t)3*N_NODESC*5*4);
  float* aeC3 =(float*)alloc((size_t)3*N_EDGESC*5*4);
  float* wE   =(float*)alloc((size_t)N_EDGESC*5*4);
  float* lattr=(float*)alloc((size_t)N_NODESC*10*4);
  float* eattrC=(float*)alloc((size_t)N_EDGESC*10*4);
  float* ve3  =(float*)alloc(256*4);
  float* VS0  =(float*)alloc(320*4);
  float* VD0  =(float*)alloc(320*4);
  float* V2   =(float*)alloc((size_t)HC*15*4);
  float* cbv  =(float*)alloc(64*4);
  float* pnode=(float*)alloc((size_t)N_NODESC*4);
  int* cntI   =(int*)alloc((size_t)N_NODESC*4);
  int* rptr   =(int*)alloc((size_t)N_NODESC*4);
  int* pos    =(int*)alloc((size_t)N_NODESC*4);
  int* srcE   =(int*)alloc((size_t)N_EDGESC*4);
  int* dstC   =(int*)alloc((size_t)N_EDGESC*4);

  hipMemsetAsync(cntI,0,(size_t)N_NODESC*4,stream);

  k_count<<<(N_EDGESC+255)/256,256,0,stream>>>(dstp,cntI);
  k_scan<<<1,1024,0,stream>>>(cntI,rptr,pos);
  k_scatter<<<(N_EDGESC+255)/256,256,0,stream>>>(dstp,srcp,eattr,pos,srcE,dstC,eattrC);
  k_loop_attr<<<(N_NODESC+3)/4,256,0,stream>>>(eattrC,rptr,cntI,lattr);
  k_padxb<<<(N_NODESC*64+255)/256,256,0,stream>>>(x,xb);
  k_ve3<<<1,256,0,stream>>>(We[0],aedge[0],We[1],aedge[1],We[2],aedge[2],ve3);
  k_vs0<<<1,384,0,stream>>>(W[0],asrc[0],adst[0],bias[2],Wlin,VS0,VD0,cbv);
  k_vq2<<<(HC*15+255)/256,256,0,stream>>>(W[2],asrc[2],adst[2],Wlin,V2);
  {
    int tot=WB2+HC*HC;
    k_conv_w3<<<(tot+255)/256,256,0,stream>>>(W[0],W[1],W[2],Bthi3,Btlo3);
  }
  k_alar0<<<(N_NODESC*5+255)/256,256,0,stream>>>(x,VS0,VD0,al,ar);
  {
    const int NEDGET=N_EDGESC+N_NODESC*5;
    k_edge_terms3<<<(3*NEDGET+255)/256,256,0,stream>>>(eattrC,lattr,ve3,srcE,dstC,al,ar,aeC3,ael3,wE);
  }

  const int NBLK0=5*((N_NODESC+127)/128);
  const int NBLK64=5*((N_NODESC+63)/64);

  // ---- L0: aggregate-then-transform (wE already built by k_edge_terms3) ----
  k_aggx<<<(N_NODESC+3)/4,256,0,stream>>>(xb,srcE,rptr,cntI,al,ar,ael3,wE,aggx,den0);
  k_gemm_l0b<<<NBLK0,256,0,stream>>>(aggx,Bthi3+WB0,Btlo3+WB0,den0,bias[0],Ahi,N_NODESC,NBLK0);

  // ---- L1 (agg fused with L2 linear functionals) ----
  {
    const float* aeL = aeC3 + (size_t)1*N_EDGESC*5;
    const float* aelL= ael3 + (size_t)1*N_NODESC*5;
    k_gemm64<<<NBLK64,256,0,stream>>>(Ahi,Bthi3+WB1,
        asrc[1],adst[1],hb,al,ar,N_NODESC,HC,NBLK64);
    k_edgew<<<(N_EDGESC+255)/256,256,0,stream>>>(srcE,dstC,al,ar,aeL,wE);
    k_agg<<<(N_NODESC+3)/4,256,0,stream>>>(hb,srcE,rptr,cntI,al,ar,aelL,wE,bias[1],V2,al2,ar2,qn);
  }
  // ---- L2 ----
  {
    const float* aelL= ael3 + (size_t)2*N_NODESC*5;
    k_agg_last<<<(N_NODESC+15)/16,256,0,stream>>>(qn,srcE,rptr,cntI,al2,ar2,aelL,aeC3+(size_t)2*N_EDGESC*5,cbv,pnode);
  }
  k_graphout<<<(NGRAPH+3)/4,256,0,stream>>>(pnode,batch,blin,out);
}

// Round 23
// 363.697 us; speedup vs baseline: 1.0671x; 1.0671x over previous
//
#include <hip/hip_runtime.h>

#define N_NODESC 20000
#define N_EDGESC 320000
#define HC 640
#define NGRAPH 500

typedef unsigned short u16;
typedef unsigned int u32;
typedef __attribute__((ext_vector_type(8))) short bf16x8;
typedef __attribute__((ext_vector_type(4))) float f32x4;

__device__ __forceinline__ float wred_sum(float v){
  #pragma unroll
  for(int o=32;o;o>>=1) v += __shfl_xor(v,o,64);
  return v;
}
__device__ __forceinline__ float lrelu(float x){ return x>0.f? x:0.2f*x; }

__device__ __forceinline__ u16 f2bf(float f){
  u32 u=__float_as_uint(f);
  u32 r=u+0x7FFFu+((u>>16)&1u);
  return (u16)(r>>16);
}
__device__ __forceinline__ float bf2f(u16 s){ return __uint_as_float(((u32)s)<<16); }
__device__ __forceinline__ float bflo(u32 w){ return __uint_as_float(w<<16); }
__device__ __forceinline__ float bfhi(u32 w){ return __uint_as_float(w&0xFFFF0000u); }

__device__ __forceinline__ void gload16(const void* g, void* l){
  __builtin_amdgcn_global_load_lds((const __attribute__((address_space(1))) void*)g,
                                   (__attribute__((address_space(3))) void*)l, 16, 0, 0);
}

// fragment-order offset (u16 units): rows (mult 16), K cols (mult 32).
__device__ __forceinline__ size_t fidx(int r, int k, int KB){
  return ((size_t)(r>>4)*KB + (k>>5))*512 + (((k>>3)&3)*16 + (r&15))*8 + (k&7);
}

// ---------------- graph preprocessing ----------------

__global__ void k_count(const int* __restrict__ dst, int* __restrict__ cnt){
  int i=blockIdx.x*blockDim.x+threadIdx.x;
  if(i>=N_EDGESC) return;
  atomicAdd(&cnt[dst[i]],1);
}

__global__ void k_scan(const int* __restrict__ cnt, int* __restrict__ rptr, int* __restrict__ pos){
  __shared__ int ps[1024];
  int t=threadIdx.x;
  const int CH=20;
  int beg=t*CH, end=min(beg+CH, N_NODESC);
  int s=0;
  for(int i=beg;i<end;i++) s+=cnt[i];
  ps[t]=s; __syncthreads();
  for(int off=1;off<1024;off<<=1){
    int v=(t>=off)? ps[t-off]:0;
    __syncthreads();
    ps[t]+=v;
    __syncthreads();
  }
  int base=ps[t]-s;
  for(int i=beg;i<end;i++){ rptr[i]=base; pos[i]=base; base+=cnt[i]; }
}

// scatter + CSR edge-data resolution in ONE pass
__global__ void k_scatter(const int* __restrict__ dst, const int* __restrict__ src,
                          const float* __restrict__ eattr, int* __restrict__ pos,
                          int* __restrict__ srcE, int* __restrict__ dstC,
                          float* __restrict__ eattrC){
  int i=blockIdx.x*blockDim.x+threadIdx.x;
  if(i>=N_EDGESC) return;
  int d=dst[i];
  int j=atomicAdd(&pos[d],1);
  dstC[j]=d;
  srcE[j]=src[i];
  const float* ep=&eattr[(size_t)i*10];
  float* op=&eattrC[(size_t)j*10];
  #pragma unroll
  for(int k=0;k<10;k++) op[k]=ep[k];
}

__global__ __launch_bounds__(256) void k_loop_attr(const float* __restrict__ eattrC,
    const int* __restrict__ rptr, const int* __restrict__ cnt,
    float* __restrict__ lattr){
  int tid=threadIdx.x, lane=tid&63;
  int n=blockIdx.x*4+(tid>>6);
  if(n>=N_NODESC) return;
  int beg=rptr[n], deg=cnt[n];
  float s[10]={0,0,0,0,0,0,0,0,0,0};
  for(int off=lane; off<deg; off+=64){
    const float* ep=&eattrC[(size_t)(beg+off)*10];
    #pragma unroll
    for(int k=0;k<10;k++) s[k]+=ep[k];
  }
  float inv=1.f/fmaxf((float)deg,1.f);
  #pragma unroll
  for(int k=0;k<10;k++){
    float tot=wred_sum(s[k]);
    if(lane==0) lattr[(size_t)n*10+k]=tot*inv;
  }
}

// ---------------- conversions ----------------

// x [20000][43] -> padded bf16 xb [20000][64]
__global__ void k_padxb(const float* __restrict__ x, u16* __restrict__ xb){
  int idx=blockIdx.x*blockDim.x+threadIdx.x;
  if(idx>=N_NODESC*64) return;
  int n=idx>>6, kk=idx&63;
  float v = kk<43 ? x[n*43+kk] : 0.f;
  xb[idx]=f2bf(v);
}

// all 3 layers' transposed weights, fragment-order within each packed region.
__global__ void k_conv_w3(const float* __restrict__ W0, const float* __restrict__ W1,
                          const float* __restrict__ W2,
                          u16* __restrict__ hi, u16* __restrict__ lo){
  const int R0=HC*64, R1=R0+HC*HC;
  const int TOT=R1+HC*HC;
  int idx=blockIdx.x*blockDim.x+threadIdx.x;
  if(idx>=TOT) return;
  const float* W; int local, KP, KL, base;
  if(idx<R0){ W=W0; local=idx; KP=64; KL=43; base=0; }
  else if(idx<R1){ W=W1; local=idx-R0; KP=HC; KL=HC; base=R0; }
  else { W=W2; local=idx-R1; KP=HC; KL=HC; base=R1; }
  int n=local/KP, kk=local-n*KP;
  float v = kk<KL ? W[(size_t)kk*HC+n] : 0.f;
  u16 h=f2bf(v);
  size_t off=(size_t)base + fidx(n,kk,KP>>5);
  hi[off]=h;
  lo[off]=f2bf(v-bf2f(h));
}

// ---------------- attention-term kernels ----------------

__global__ void k_ve3(const float* __restrict__ We0, const float* __restrict__ ae0,
                      const float* __restrict__ We1, const float* __restrict__ ae1,
                      const float* __restrict__ We2, const float* __restrict__ ae2,
                      float* __restrict__ ve3){
  int t=threadIdx.x;
  if(t>=150) return;
  int L=t/50, r=t-50*L, k=r/5, h=r%5;
  const float* We = (L==0)?We0:(L==1)?We1:We2;
  const float* ae = (L==0)?ae0:(L==1)?ae1:ae2;
  float s=0.f;
  for(int c=0;c<128;c++) s += We[k*HC + h*128 + c]*ae[h*128+c];
  ve3[t]=s;
}

// VS0/VD0 (W0^T a vectors) + cb = dot(bias2,wlin) (wave 5). 384 threads.
__global__ void k_vs0(const float* __restrict__ W0, const float* __restrict__ asrc,
                      const float* __restrict__ adst,
                      const float* __restrict__ bias2, const float* __restrict__ wlin,
                      float* __restrict__ VS, float* __restrict__ VD,
                      float* __restrict__ cb){
  int t=threadIdx.x;
  if(t<320){
    int k=t/5, h=t%5;
    float sv=0.f, dv=0.f;
    if(k<43){
      for(int c=0;c<128;c++){
        float wv=W0[(size_t)k*HC + h*128 + c];
        sv+=wv*asrc[h*128+c];
        dv+=wv*adst[h*128+c];
      }
    }
    VS[t]=sv; VD[t]=dv;
  }else{
    int lane=t-320;
    float s=0.f;
    for(int c=lane;c<HC;c+=64) s+=bias2[c]*wlin[c];
    s=wred_sum(s);
    if(lane==0) cb[0]=s;
  }
}

// V2[k][o] for L2 linear functionals: o=0..4 al(asrc2), 5..9 ar(adst2), 10..14 q(wlin)
__global__ void k_vq2(const float* __restrict__ W2, const float* __restrict__ asrc,
                      const float* __restrict__ adst, const float* __restrict__ wlin,
                      float* __restrict__ V2){
  int t=blockIdx.x*blockDim.x+threadIdx.x;
  if(t>=HC*15) return;
  int k=t/15, o=t-15*k;
  int h=o%5, grp=o/5;
  const float* v = (grp==0)? asrc : (grp==1)? adst : wlin;
  const float* wr=&W2[(size_t)k*HC + h*128];
  const float* vr=&v[h*128];
  float s=0.f;
  for(int c=0;c<128;c++) s+=wr[c]*vr[c];
  V2[t]=s;
}

// al0/ar0 = x @ VS0 / VD0
__global__ __launch_bounds__(256) void k_alar0(const float* __restrict__ x,
    const float* __restrict__ VS, const float* __restrict__ VD,
    float* __restrict__ al, float* __restrict__ ar){
  __shared__ float vs[320], vd[320];
  if(threadIdx.x<320){ vs[threadIdx.x]=VS[threadIdx.x]; vd[threadIdx.x]=VD[threadIdx.x]; }
  __syncthreads();
  int idx=blockIdx.x*blockDim.x+threadIdx.x;
  if(idx>=N_NODESC*5) return;
  int n=idx/5, h=idx-5*n;
  float sa=0.f, sd=0.f;
  const float* xr=&x[(size_t)n*43];
  for(int k=0;k<43;k++){
    float xv=xr[k];
    sa+=xv*vs[k*5+h];
    sd+=xv*vd[k*5+h];
  }
  al[idx]=sa; ar[idx]=sd;
}

// Layers 1/2: aeC; layer 0: wE0 directly (al0/ar0 ready). Also ael3 for all.
__global__ __launch_bounds__(256) void k_edge_terms3(const float* __restrict__ eattrC,
    const float* __restrict__ lattr, const float* __restrict__ ve3,
    const int* __restrict__ srcE, const int* __restrict__ dstC,
    const float* __restrict__ al0, const float* __restrict__ ar0,
    float* __restrict__ aeC3, float* __restrict__ ael3, float* __restrict__ wE0){
  __shared__ float ves[150];
  if(threadIdx.x<150) ves[threadIdx.x]=ve3[threadIdx.x];
  __syncthreads();
  const int NEDGET=N_EDGESC+N_NODESC*5;
  int idx=blockIdx.x*blockDim.x+threadIdx.x;
  if(idx>=3*NEDGET) return;
  int L=idx/NEDGET, r=idx-L*NEDGET;
  const float* vl=&ves[L*50];
  if(r<N_EDGESC){
    float ev[10];
    const float* ep=&eattrC[(size_t)r*10];
    #pragma unroll
    for(int k=0;k<10;k++) ev[k]=ep[k];
    if(L==0){
      int s=srcE[r], d=dstC[r];
      #pragma unroll
      for(int hh=0;hh<5;hh++){
        float sum=0.f;
        #pragma unroll
        for(int k=0;k<10;k++) sum+=ev[k]*vl[k*5+hh];
        wE0[(size_t)r*5+hh]=__expf(lrelu(al0[s*5+hh]+ar0[d*5+hh]+sum));
      }
    }else{
      #pragma unroll
      for(int hh=0;hh<5;hh++){
        float sum=0.f;
        #pragma unroll
        for(int k=0;k<10;k++) sum+=ev[k]*vl[k*5+hh];
        aeC3[(size_t)L*N_EDGESC*5 + (size_t)r*5+hh]=sum;
      }
    }
  }else{
    int t=r-N_EDGESC;
    int n=t/5, h=t-5*n;
    float s=0.f;
    #pragma unroll
    for(int k=0;k<10;k++) s+=lattr[(size_t)n*10+k]*vl[k*5+h];
    ael3[(size_t)L*N_NODESC*5 + t]=s;
  }
}

// per-layer edge softmax weights (edge-parallel) — L1 only
__global__ void k_edgew(const int* __restrict__ srcE, const int* __restrict__ dstC,
                        const float* __restrict__ al, const float* __restrict__ ar,
                        const float* __restrict__ aeC, float* __restrict__ wE){
  int j=blockIdx.x*blockDim.x+threadIdx.x;
  if(j>=N_EDGESC) return;
  int s=srcE[j], d=dstC[j];
  const float* av=&aeC[(size_t)j*5];
  float* wp=&wE[(size_t)j*5];
  #pragma unroll
  for(int h=0;h<5;h++)
    wp[h]=__expf(lrelu(al[s*5+h]+ar[d*5+h]+av[h]));
}

// ---------------- L0: aggregate-then-transform ----------------

__global__ __launch_bounds__(256) void k_aggx(const u16* __restrict__ xb,
    const int* __restrict__ srcE, const int* __restrict__ rptr, const int* __restrict__ cnt,
    const float* __restrict__ al, const float* __restrict__ ar, const float* __restrict__ ael,
    const float* __restrict__ wE,
    u16* __restrict__ aggx, float* __restrict__ den0){
  const size_t HSZ=(size_t)N_NODESC*64;
  int tid=threadIdx.x, lane=tid&63;
  int n=blockIdx.x*4+(tid>>6);
  if(n>=N_NODESC) return;
  float den[5], acc[5];
  #pragma unroll
  for(int h=0;h<5;h++)
    den[h]=__expf(lrelu(al[n*5+h]+ar[n*5+h]+ael[n*5+h]));   // p0
  float xn=bf2f(xb[(size_t)n*64+lane]);
  #pragma unroll
  for(int h=0;h<5;h++) acc[h]=den[h]*xn;
  int beg=rptr[n], end=beg+cnt[n];
  int j=beg;
  for(; j+7<end; j+=8){
    int sj[8]; float xv[8];
    #pragma unroll
    for(int u=0;u<8;u++) sj[u]=srcE[j+u];
    #pragma unroll
    for(int u=0;u<8;u++) xv[u]=bf2f(xb[(size_t)sj[u]*64+lane]);
    #pragma unroll
    for(int u=0;u<8;u++){
      const float* wp=&wE[(size_t)(j+u)*5];
      #pragma unroll
      for(int h=0;h<5;h++){
        float w=wp[h];
        den[h]+=w;
        acc[h]+=w*xv[u];
      }
    }
  }
  for(; j<end; j++){
    int sj=srcE[j];
    float xv=bf2f(xb[(size_t)sj*64+lane]);
    const float* wp=&wE[(size_t)j*5];
    #pragma unroll
    for(int h=0;h<5;h++){
      float w=wp[h];
      den[h]+=w;
      acc[h]+=w*xv;
    }
  }
  size_t fo=fidx(n,lane,2);
  #pragma unroll
  for(int h=0;h<5;h++) aggx[(size_t)h*HSZ+fo]=f2bf(acc[h]);
  if(lane<5) den0[(size_t)n*5+lane]=den[lane];
}

// L0 GEMM on aggregated inputs (per-head), 128x128, 2 K-steps, dbuf.
__global__ __launch_bounds__(256,3) void k_gemm_l0b(
    const u16* __restrict__ AGX,
    const u16* __restrict__ Bhi, const u16* __restrict__ Blo,
    const float* __restrict__ den0, const float* __restrict__ bias,
    u16* __restrict__ A1, int M, int nblk){
  const size_t HSZ=(size_t)N_NODESC*64;
  __shared__ u16 lds[2*3*4096];
  int tid=threadIdx.x;
  int lane=tid&63;
  int w=tid>>6;
  int l15=lane&15, lg=lane>>4;
  int orig=blockIdx.x;
  int q=nblk>>3, r=nblk&7;
  int xcd=orig&7, off=orig>>3;
  int wg=(xcd<r? xcd*(q+1) : r*(q+1)+(xcd-r)*q)+off;
  int by=wg/5, bx=wg-5*by;
  int row0=by*128, col0=bx*128;
  int wr=w>>1, wc=w&1;
  const u16* A=AGX+(size_t)bx*HSZ;

  f32x4 zero = {0.f,0.f,0.f,0.f};
  f32x4 acc[4][4];
  #pragma unroll
  for(int i=0;i<4;i++)
    #pragma unroll
    for(int j=0;j<4;j++) acc[i][j]=zero;

  auto stage=[&](int b, int k0){
    u16* base = lds + b*3*4096;
    int kb=k0>>5;
    #pragma unroll
    for(int c=0;c<2;c++){
      int sb=w+4*c;
      size_t af=((size_t)((row0>>4)+sb)*2 + kb)*512 + lane*8;
      size_t bf=((size_t)((col0>>4)+sb)*2 + kb)*512 + lane*8;
      gload16(A+af, base + sb*512);
      gload16(Bhi+bf, base+4096 + sb*512);
      gload16(Blo+bf, base+8192 + sb*512);
    }
  };

  stage(0,0);
  __syncthreads();
  int cur=0;
  for(int t=0;t<2;t++){
    if(t==0) stage(1,32);
    u16* cb = lds + cur*3*4096;
    bf16x8 ah[4], bh[4], bl[4];
    #pragma unroll
    for(int i=0;i<4;i++){
      ah[i]=*(const bf16x8*)&cb[(wr*4+i)*512 + lane*8];
      bh[i]=*(const bf16x8*)&cb[4096+(wc*4+i)*512 + lane*8];
      bl[i]=*(const bf16x8*)&cb[8192+(wc*4+i)*512 + lane*8];
    }
    #pragma unroll
    for(int i=0;i<4;i++)
      #pragma unroll
      for(int j=0;j<4;j++){
        acc[i][j]=__builtin_amdgcn_mfma_f32_16x16x32_bf16(ah[i],bh[j],acc[i][j],0,0,0);
        acc[i][j]=__builtin_amdgcn_mfma_f32_16x16x32_bf16(ah[i],bl[j],acc[i][j],0,0,0);
      }
    __syncthreads();
    cur^=1;
  }

  #pragma unroll
  for(int i=0;i<4;i++){
    #pragma unroll
    for(int j=0;j<4;j++){
      int col=col0+wc*64+j*16+l15;
      float bv=bias[col];
      #pragma unroll
      for(int rr=0;rr<4;rr++){
        int row=row0+wr*64+i*16+lg*4+rr;
        if(row<M){
          float dv=den0[(size_t)row*5+bx];
          float v=acc[i][j][rr]/(dv+1e-16f)+bv;
          v=fmaxf(v,0.f);
          A1[fidx(row,col,20)]=f2bf(v);
        }
      }
    }
  }
}

// ---------------- L1 GEMM (64x128 tile, fragment-order) ----------------
// Quad-buffered, prefetch distance 2, counted vmcnt, one barrier per K-step.

__global__ __launch_bounds__(256,3) void k_gemm64(
    const u16* __restrict__ A,
    const u16* __restrict__ B,
    const float* __restrict__ asrc, const float* __restrict__ adst,
    u16* __restrict__ hb, float* __restrict__ al, float* __restrict__ ar,
    int M, int KP, int nblk){
  __shared__ u16 lds[4*6144];
  int tid=threadIdx.x;
  int lane=tid&63;
  int w=tid>>6;
  int l15=lane&15, lg=lane>>4;
  int orig=blockIdx.x;
  int q=nblk>>3, r=nblk&7;
  int xcd=orig&7, off=orig>>3;
  int wg=(xcd<r? xcd*(q+1) : r*(q+1)+(xcd-r)*q)+off;
  int by=wg/5, bx=wg-5*by;
  int row0=by*64, col0=bx*128;
  int KB=KP>>5;

  f32x4 zero = {0.f,0.f,0.f,0.f};
  f32x4 acc[4][2];
  #pragma unroll
  for(int i=0;i<4;i++){ acc[i][0]=zero; acc[i][1]=zero; }

  auto stage=[&](int b, int k0){
    u16* base = lds + b*6144;
    int kb=k0>>5;
    size_t af=((size_t)((row0>>4)+w)*KB + kb)*512 + lane*8;
    gload16(A+af, base + w*512);
    #pragma unroll
    for(int c=0;c<2;c++){
      int sb=w+4*c;
      size_t bf=((size_t)((col0>>4)+sb)*KB + kb)*512 + lane*8;
      gload16(B+bf, base+2048 + sb*512);
    }
  };

  int nt=KP/32;
  stage(0,0);
  stage(1,32);
  for(int t=0;t<nt;t++){
    int nb=t+2;
    if(nb<nt) stage(nb&3, nb*32);
    if(nb<nt)      { asm volatile("s_waitcnt vmcnt(6)" ::: "memory"); }
    else if(t+1<nt){ asm volatile("s_waitcnt vmcnt(3)" ::: "memory"); }
    else           { asm volatile("s_waitcnt vmcnt(0)" ::: "memory"); }
    __builtin_amdgcn_sched_barrier(0);
    __builtin_amdgcn_s_barrier();
    u16* cb = lds + (t&3)*6144;
    bf16x8 ah[4], bh[2];
    #pragma unroll
    for(int i=0;i<4;i++) ah[i]=*(const bf16x8*)&cb[i*512 + lane*8];
    #pragma unroll
    for(int j=0;j<2;j++) bh[j]=*(const bf16x8*)&cb[2048+(w*2+j)*512 + lane*8];
    #pragma unroll
    for(int i=0;i<4;i++){
      acc[i][0]=__builtin_amdgcn_mfma_f32_16x16x32_bf16(ah[i],bh[0],acc[i][0],0,0,0);
      acc[i][1]=__builtin_amdgcn_mfma_f32_16x16x32_bf16(ah[i],bh[1],acc[i][1],0,0,0);
    }
  }
  __syncthreads();

  float asv[2], adv[2];
  #pragma unroll
  for(int j=0;j<2;j++){
    int c=col0+w*32+j*16+l15;
    asv[j]=asrc[c]; adv[j]=adst[c];
  }
  #pragma unroll
  for(int i=0;i<4;i++){
    #pragma unroll
    for(int j=0;j<2;j++){
      #pragma unroll
      for(int rr=0;rr<4;rr++){
        int row=row0+i*16+lg*4+rr;
        if(row<M)
          hb[(size_t)row*HC + ((w&1)*32+j*16+l15)*10 + bx*2+(w>>1)]=f2bf(acc[i][j][rr]);
      }
    }
  }
  float* redAl=(float*)lds;
  float* redAr=redAl+256;
  #pragma unroll
  for(int i=0;i<4;i++){
    #pragma unroll
    for(int rr=0;rr<4;rr++){
      float sa=0.f, sd=0.f;
      #pragma unroll
      for(int j=0;j<2;j++){
        sa+=acc[i][j][rr]*asv[j];
        sd+=acc[i][j][rr]*adv[j];
      }
      #pragma unroll
      for(int o=1;o<16;o<<=1){
        sa+=__shfl_xor(sa,o,64); sd+=__shfl_xor(sd,o,64);
      }
      if(l15==0){
        int lr=i*16+lg*4+rr;
        redAl[lr*4+w]=sa; redAr[lr*4+w]=sd;
      }
    }
  }
  __syncthreads();
  if(tid<64){
    int row=row0+tid;
    if(row<M){
      al[(size_t)row*5+bx]=redAl[tid*4]+redAl[tid*4+1]+redAl[tid*4+2]+redAl[tid*4+3];
      ar[(size_t)row*5+bx]=redAr[tid*4]+redAr[tid*4+1]+redAr[tid*4+2]+redAr[tid*4+3];
    }
  }
}

// L1 aggregation; one wave per node; precomputed wE; fragment-order output (A2).
__global__ __launch_bounds__(256) void k_agg(const u16* __restrict__ hb, const int* __restrict__ srcE,
    const int* __restrict__ rptr, const int* __restrict__ cnt,
    const float* __restrict__ al, const float* __restrict__ ar, const float* __restrict__ ael,
    const float* __restrict__ wE, const float* __restrict__ bias,
    u16* __restrict__ ohi){
  int tid=threadIdx.x, lane=tid&63;
  int n=blockIdx.x*4+(tid>>6);
  if(n>=N_NODESC) return;
  float den[5], acc[10];
  #pragma unroll
  for(int h=0;h<5;h++)
    den[h]=__expf(lrelu(al[n*5+h]+ar[n*5+h]+ael[n*5+h]));
  {
    const u32* sp=(const u32*)(hb+(size_t)n*HC+lane*10);
    #pragma unroll
    for(int j2=0;j2<5;j2++){
      u32 wv=sp[j2];
      acc[2*j2]  =den[j2]*bflo(wv);
      acc[2*j2+1]=den[j2]*bfhi(wv);
    }
  }
  int beg=rptr[n], end=beg+cnt[n];
  int j=beg;
  for(; j+3<end; j+=4){
    int sj[4];
    #pragma unroll
    for(int u=0;u<4;u++) sj[u]=srcE[j+u];
    float w[4][5];
    #pragma unroll
    for(int u=0;u<4;u++){
      const float* wp=&wE[(size_t)(j+u)*5];
      #pragma unroll
      for(int h=0;h<5;h++) w[u][h]=wp[h];
    }
    u32 wv[4][5];
    #pragma unroll
    for(int u=0;u<4;u++){
      const u32* hr=(const u32*)(hb+(size_t)sj[u]*HC+lane*10);
      #pragma unroll
      for(int j2=0;j2<5;j2++) wv[u][j2]=hr[j2];
    }
    #pragma unroll
    for(int u=0;u<4;u++){
      #pragma unroll
      for(int j2=0;j2<5;j2++){
        den[j2]+=w[u][j2];
        acc[2*j2]  +=w[u][j2]*bflo(wv[u][j2]);
        acc[2*j2+1]+=w[u][j2]*bfhi(wv[u][j2]);
      }
    }
  }
  for(; j<end; j++){
    int sj=srcE[j];
    const float* wp=&wE[(size_t)j*5];
    float w[5];
    #pragma unroll
    for(int h=0;h<5;h++){ w[h]=wp[h]; den[h]+=w[h]; }
    const u32* hr=(const u32*)(hb+(size_t)sj*HC+lane*10);
    #pragma unroll
    for(int j2=0;j2<5;j2++){
      u32 wv=hr[j2];
      acc[2*j2]  +=w[j2]*bflo(wv);
      acc[2*j2+1]+=w[j2]*bfhi(wv);
    }
  }
  #pragma unroll
  for(int k=0;k<10;k++){
    int ccol=lane+64*k;
    float vv=acc[k]/(den[k>>1]+1e-16f)+bias[ccol];
    vv=fmaxf(vv,0.f);
    ohi[fidx(n,ccol,20)]=f2bf(vv);
  }
}

// L2 linear functionals: al2/ar2/qn = A2 @ V2 (skinny 640->15).
// One block = 16 nodes; 4 waves split the 20 k-subblocks; V2 in LDS.
__global__ __launch_bounds__(256) void k_qal2(const u16* __restrict__ A2,
    const float* __restrict__ V2,
    float* __restrict__ al, float* __restrict__ ar, float* __restrict__ qn){
  __shared__ float Vs[HC*15];
  __shared__ float red[4][16][15];
  int tid=threadIdx.x, lane=tid&63, w=tid>>6;
  for(int i=tid;i<HC*15;i+=256) Vs[i]=V2[i];
  __syncthreads();
  int nb=blockIdx.x;
  int koct=lane>>4;
  float acc[15];
  #pragma unroll
  for(int o=0;o<15;o++) acc[o]=0.f;
  for(int kb=w*5; kb<w*5+5; kb++){
    bf16x8 v=*(const bf16x8*)&A2[((size_t)nb*20+kb)*512 + (size_t)lane*8];
    #pragma unroll
    for(int e=0;e<8;e++){
      float xv=bf2f((u16)v[e]);
      int k=kb*32+koct*8+e;
      const float* vp=&Vs[k*15];
      #pragma unroll
      for(int o=0;o<15;o++) acc[o]+=xv*vp[o];
    }
  }
  #pragma unroll
  for(int o=0;o<15;o++){
    acc[o]+=__shfl_xor(acc[o],16,64);
    acc[o]+=__shfl_xor(acc[o],32,64);
  }
  if((lane&15)==lane){
    #pragma unroll
    for(int o=0;o<15;o++) red[w][lane][o]=acc[o];
  }
  __syncthreads();
  if(tid<240){
    int node=tid/15, o=tid-15*node;
    float s=red[0][node][o]+red[1][node][o]+red[2][node][o]+red[3][node][o];
    int n=nb*16+node;
    if(o<5)       al[(size_t)n*5+o]=s;
    else if(o<10) ar[(size_t)n*5+(o-5)]=s;
    else          qn[(size_t)n*5+(o-10)]=s;
  }
}

// last-layer agg fused with pooling dot (q summary, L2-resident).
__global__ __launch_bounds__(256) void k_agg_last(const float* __restrict__ qn,
    const int* __restrict__ srcE, const int* __restrict__ rptr, const int* __restrict__ cnt,
    const float* __restrict__ al, const float* __restrict__ ar, const float* __restrict__ ael,
    const float* __restrict__ aeC, const float* __restrict__ cb,
    float* __restrict__ pnode){
  int tid=threadIdx.x;
  int sub=tid&15;
  int n=blockIdx.x*16+(tid>>4);
  if(n>=N_NODESC) return;
  float arn[5], den[5], qs[5];
  #pragma unroll
  for(int h=0;h<5;h++) arn[h]=ar[n*5+h];
  #pragma unroll
  for(int h=0;h<5;h++){ den[h]=0.f; qs[h]=0.f; }
  if(sub==0){
    #pragma unroll
    for(int h=0;h<5;h++){
      float pp=__expf(lrelu(al[n*5+h]+arn[h]+ael[n*5+h]));
      den[h]=pp; qs[h]=pp*qn[(size_t)n*5+h];
    }
  }
  int beg=rptr[n], deg=cnt[n];
  for(int off=sub; off<deg; off+=16){
    int j=beg+off;
    int s=srcE[j];
    const float* av=&aeC[(size_t)j*5];
    const float* qv=&qn[(size_t)s*5];
    #pragma unroll
    for(int h=0;h<5;h++){
      float pp=__expf(lrelu(al[s*5+h]+arn[h]+av[h]));
      den[h]+=pp; qs[h]+=pp*qv[h];
    }
  }
  #pragma unroll
  for(int h=0;h<5;h++){
    #pragma unroll
    for(int o=1;o<16;o<<=1){
      den[h]+=__shfl_xor(den[h],o,16);
      qs[h]+=__shfl_xor(qs[h],o,16);
    }
  }
  if(sub==0){
    float s=0.f;
    #pragma unroll
    for(int h=0;h<5;h++) s+=qs[h]/(den[h]+1e-16f);
    pnode[n]=s+cb[0];
  }
}

// per-graph mean over sorted batch segments
__global__ __launch_bounds__(256) void k_graphout(const float* __restrict__ pnode,
    const int* __restrict__ batch, const float* __restrict__ blin,
    float* __restrict__ out){
  int tid=threadIdx.x, lane=tid&63;
  int g=blockIdx.x*4+(tid>>6);
  if(g>=NGRAPH) return;
  auto lb=[&](int val){
    int lo=0, hi=N_NODESC;
    while(lo<hi){ int mid=(lo+hi)>>1; if(batch[mid]<val) lo=mid+1; else hi=mid; }
    return lo;
  };
  int s0=lb(g), s1=lb(g+1);
  float s=0.f;
  for(int i=s0+lane;i<s1;i+=64) s+=pnode[i];
  s=wred_sum(s);
  if(lane==0) out[g]=s/fmaxf((float)(s1-s0),1.f)+blin[0];
}

// ---------------- launch ----------------

extern "C" void kernel_launch(void* const* d_in, const int* in_sizes, int n_in,
                              void* d_out, int out_size, void* d_ws, size_t ws_size,
                              hipStream_t stream){
  const float* x     = (const float*)d_in[0];
  const float* eattr = (const float*)d_in[1];
  const float* W[3]    ={(const float*)d_in[2],(const float*)d_in[8],(const float*)d_in[14]};
  const float* We[3]   ={(const float*)d_in[3],(const float*)d_in[9],(const float*)d_in[15]};
  const float* asrc[3] ={(const float*)d_in[4],(const float*)d_in[10],(const float*)d_in[16]};
  const float* adst[3] ={(const float*)d_in[5],(const float*)d_in[11],(const float*)d_in[17]};
  const float* aedge[3]={(const float*)d_in[6],(const float*)d_in[12],(const float*)d_in[18]};
  const float* bias[3] ={(const float*)d_in[7],(const float*)d_in[13],(const float*)d_in[19]};
  const float* Wlin  = (const float*)d_in[20];
  const float* blin  = (const float*)d_in[21];
  const int* eind    = (const int*)d_in[22];
  const int* srcp    = eind;
  const int* dstp    = eind + N_EDGESC;
  const int* batch   = (const int*)d_in[23];
  float* out = (float*)d_out;

  char* ws=(char*)d_ws;
  size_t o=0;
  auto alloc=[&](size_t bytes)->void*{ void* p=ws+o; o=(o+bytes+255)&~(size_t)255; return p; };
  u16* hb   =(u16*)alloc((size_t)N_NODESC*HC*2);           // h1 node-major (L1 gather)
  u16* Ahi =(u16*)alloc((size_t)N_NODESC*HC*2);            // A1/A2 (fragment-order)
  u16* xb  =(u16*)alloc((size_t)N_NODESC*64*2);            // padded bf16 x
  u16* aggx=(u16*)alloc((size_t)5*N_NODESC*64*2);          // L0 aggregated per-head
  const int WB0=0, WB1=HC*64, WB2=WB1+HC*HC;
  u16* Bthi3=(u16*)alloc((size_t)(WB2+HC*HC)*2);
  u16* Btlo3=(u16*)alloc((size_t)(WB2+HC*HC)*2);
  float* al   =(float*)alloc((size_t)N_NODESC*5*4);
  float* ar   =(float*)alloc((size_t)N_NODESC*5*4);
  float* al2  =(float*)alloc((size_t)N_NODESC*5*4);
  float* ar2  =(float*)alloc((size_t)N_NODESC*5*4);
  float* qn   =(float*)alloc((size_t)N_NODESC*5*4);
  float* den0 =(float*)alloc((size_t)N_NODESC*5*4);
  float* ael3 =(float*)alloc((size_t)3*N_NODESC*5*4);
  float* aeC3 =(float*)alloc((size_t)3*N_EDGESC*5*4);
  float* wE   =(float*)alloc((size_t)N_EDGESC*5*4);
  float* lattr=(float*)alloc((size_t)N_NODESC*10*4);
  float* eattrC=(float*)alloc((size_t)N_EDGESC*10*4);
  float* ve3  =(float*)alloc(256*4);
  float* VS0  =(float*)alloc(320*4);
  float* VD0  =(float*)alloc(320*4);
  float* V2   =(float*)alloc((size_t)HC*15*4);
  float* cbv  =(float*)alloc(64*4);
  float* pnode=(float*)alloc((size_t)N_NODESC*4);
  int* cntI   =(int*)alloc((size_t)N_NODESC*4);
  int* rptr   =(int*)alloc((size_t)N_NODESC*4);
  int* pos    =(int*)alloc((size_t)N_NODESC*4);
  int* srcE   =(int*)alloc((size_t)N_EDGESC*4);
  int* dstC   =(int*)alloc((size_t)N_EDGESC*4);

  hipMemsetAsync(cntI,0,(size_t)N_NODESC*4,stream);

  k_count<<<(N_EDGESC+255)/256,256,0,stream>>>(dstp,cntI);
  k_scan<<<1,1024,0,stream>>>(cntI,rptr,pos);
  k_scatter<<<(N_EDGESC+255)/256,256,0,stream>>>(dstp,srcp,eattr,pos,srcE,dstC,eattrC);
  k_loop_attr<<<(N_NODESC+3)/4,256,0,stream>>>(eattrC,rptr,cntI,lattr);
  k_padxb<<<(N_NODESC*64+255)/256,256,0,stream>>>(x,xb);
  k_ve3<<<1,256,0,stream>>>(We[0],aedge[0],We[1],aedge[1],We[2],aedge[2],ve3);
  k_vs0<<<1,384,0,stream>>>(W[0],asrc[0],adst[0],bias[2],Wlin,VS0,VD0,cbv);
  k_vq2<<<(HC*15+255)/256,256,0,stream>>>(W[2],asrc[2],adst[2],Wlin,V2);
  {
    int tot=WB2+HC*HC;
    k_conv_w3<<<(tot+255)/256,256,0,stream>>>(W[0],W[1],W[2],Bthi3,Btlo3);
  }
  k_alar0<<<(N_NODESC*5+255)/256,256,0,stream>>>(x,VS0,VD0,al,ar);
  {
    const int NEDGET=N_EDGESC+N_NODESC*5;
    k_edge_terms3<<<(3*NEDGET+255)/256,256,0,stream>>>(eattrC,lattr,ve3,srcE,dstC,al,ar,aeC3,ael3,wE);
  }

  const int NBLK0=5*((N_NODESC+127)/128);
  const int NBLK64=5*((N_NODESC+63)/64);

  // ---- L0: aggregate-then-transform (wE0 built by k_edge_terms3) ----
  k_aggx<<<(N_NODESC+3)/4,256,0,stream>>>(xb,srcE,rptr,cntI,al,ar,ael3,wE,aggx,den0);
  k_gemm_l0b<<<NBLK0,256,0,stream>>>(aggx,Bthi3+WB0,Btlo3+WB0,den0,bias[0],Ahi,N_NODESC,NBLK0);

  // ---- L1 ----
  {
    const float* aeL = aeC3 + (size_t)1*N_EDGESC*5;
    const float* aelL= ael3 + (size_t)1*N_NODESC*5;
    k_gemm64<<<NBLK64,256,0,stream>>>(Ahi,Bthi3+WB1,
        asrc[1],adst[1],hb,al,ar,N_NODESC,HC,NBLK64);
    k_edgew<<<(N_EDGESC+255)/256,256,0,stream>>>(srcE,dstC,al,ar,aeL,wE);
    k_agg<<<(N_NODESC+3)/4,256,0,stream>>>(hb,srcE,rptr,cntI,al,ar,aelL,wE,bias[1],Ahi);
  }
  // ---- L2: linear-functional shortcut (no GEMM) ----
  {
    const float* aelL= ael3 + (size_t)2*N_NODESC*5;
    k_qal2<<<N_NODESC/16,256,0,stream>>>(Ahi,V2,al2,ar2,qn);
    k_agg_last<<<(N_NODESC+15)/16,256,0,stream>>>(qn,srcE,rptr,cntI,al2,ar2,aelL,aeC3+(size_t)2*N_EDGESC*5,cbv,pnode);
  }
  k_graphout<<<(NGRAPH+3)/4,256,0,stream>>>(pnode,batch,blin,out);
}